// Round 16
// baseline (69.357 us; speedup 1.0000x reference)
//
#include <hip/hip_runtime.h>
#include <math.h>

#define NUSERS 100000
#define NITEMS 50000
#define NN (NUSERS + NITEMS)
#define EMB 64
#define NNZ_ 4000000
#define BB 4096
#define NSLOT (2 * BB)
#define CAP 128
#define FSTR 32            // fill counter stride (ints): 1 counter per 128-B line
#define BMW 4688           // bitmap words: ceil(150000/32)
#define EPSN 1e-12f
#define NT 32              // 4096 / 128 gram tiles per side
#define NTRI 528           // NT*(NT+1)/2 upper-tri tiles
#define NG (NNZ_ / 4)      // 1,000,000 int4 groups
#define NM4 (NG / 4)       // 250,000 mask words

// ws layout (bytes):
//  map        : int[NN]            @ 0        (1 MiB reserved)
//  fillp      : int[NSLOT*FSTR]    @ 1 MiB    (1 MiB)
//  bins       : uint2[NSLOT*CAP]   @ 2 MiB    (8 MiB)
//  acc        : float[NSLOT*EMB]   @ 10 MiB   (2 MiB)
//  zub        : ushort[BB*EMB]     @ 12 MiB   (512 KiB)
//  zib        : ushort[BB*EMB]     @ 12.5 MiB (512 KiB)
//  part_align : float[BB]          @ 13 MiB
//  part_reg   : float[BB]          @ 13 MiB + 16 KiB
//  gpart      : float[2*NTRI]      @ 13 MiB + 32 KiB
//  bitmap     : uint[BMW]          @ 13 MiB + 64 KiB
//  hitmask    : uchar[NG]          @ 14 MiB   (1 MiB)

typedef __attribute__((ext_vector_type(8))) short short8v;
typedef __attribute__((ext_vector_type(16))) float f32x16;

__device__ inline float wave_reduce_sum(float v) {
  #pragma unroll
  for (int off = 32; off >= 1; off >>= 1) v += __shfl_xor(v, off, 64);
  return v;
}

__device__ inline unsigned short f2bf(float f) {
  unsigned u = __float_as_uint(f);
  unsigned r = u + 0x7fffu + ((u >> 16) & 1u);
  return (unsigned short)(r >> 16);
}

__global__ __launch_bounds__(256) void lg_init(int* map, int* fillp, unsigned* bitmap) {
  int t = blockIdx.x * blockDim.x + threadIdx.x;
  if (t < NN) map[t] = -1;
  if (t < NSLOT * FSTR) fillp[t] = 0;
  if (t < BMW) bitmap[t] = 0u;
}

__global__ __launch_bounds__(256) void lg_mark(const int* __restrict__ user,
                                               const int* __restrict__ positive,
                                               int* __restrict__ map,
                                               unsigned* __restrict__ bitmap) {
  int t = blockIdx.x * blockDim.x + threadIdx.x;
  if (t >= 2 * BB) return;
  int row = (t < BB) ? user[t] : (NUSERS + positive[t - BB]);
  atomicCAS(&map[row], -1, t);
  atomicOr(&bitmap[row >> 5], 1u << (row & 31));
}

// Phase (a): pure streaming probe. No LDS, no ballots, no atomics, no
// divergence — rows stream + 4 independent bitmap gathers + 1-byte mask store.
__global__ __launch_bounds__(256) void lg_probe(const int4* __restrict__ rows4,
                                                const unsigned* __restrict__ bitmap,
                                                unsigned char* __restrict__ mask) {
  int t = blockIdx.x * 256 + threadIdx.x;
  if (t >= NG) return;
  int4 r = rows4[t];
  unsigned h = ((bitmap[r.x >> 5] >> (r.x & 31)) & 1u)
             | (((bitmap[r.y >> 5] >> (r.y & 31)) & 1u) << 1)
             | (((bitmap[r.z >> 5] >> (r.z & 31)) & 1u) << 2)
             | (((bitmap[r.w >> 5] >> (r.w & 31)) & 1u) << 3);
  mask[t] = (unsigned char)h;
}

// Phase (b): stream the 1-MB mask; enqueue hit indices per wave (LDS atomic),
// single drain with scattered reads at hit positions only.
__global__ __launch_bounds__(256) void lg_collect(const unsigned* __restrict__ mask4,
                                                  const int* __restrict__ rows,
                                                  const int* __restrict__ cols,
                                                  const float* __restrict__ vals,
                                                  const int* __restrict__ map,
                                                  int* __restrict__ fillp,
                                                  uint2* __restrict__ bins) {
  __shared__ int qk[4][1024];   // worst-case 64 lanes x 16 bits
  __shared__ int qn[4];
  int t = threadIdx.x;
  int lane = t & 63, w = t >> 6;
  if (lane == 0) qn[w] = 0;
  __syncthreads();
  int g = blockIdx.x * 256 + t;
  unsigned m = (g < NM4) ? mask4[g] : 0u;
  // bit p of m: group byte b=p>>3 (bits 4..7 of each byte are 0), elem j=p&7
  while (m) {
    int p = __ffs(m) - 1;
    m &= m - 1;
    int k = g * 16 + (p >> 3) * 4 + (p & 7);
    int pos = atomicAdd(&qn[w], 1);
    qk[w][pos] = k;
  }
  __syncthreads();
  int n = qn[w];
  for (int i = lane; i < n; i += 64) {
    int k = qk[w][i];
    int r = rows[k];
    int c = cols[k];
    float v = vals[k];
    int s = map[r];
    int pos = atomicAdd(&fillp[s * FSTR], 1);
    if (pos < CAP) bins[(size_t)s * CAP + pos] = make_uint2((unsigned)c, __float_as_uint(v));
  }
}

__global__ __launch_bounds__(256) void lg_accum(const int* __restrict__ fillp,
                                                const uint2* __restrict__ bins,
                                                const float* __restrict__ uemb,
                                                const float* __restrict__ iemb,
                                                float* __restrict__ acc) {
  int w = (blockIdx.x * blockDim.x + threadIdx.x) >> 6;
  int lane = threadIdx.x & 63;
  if (w >= NSLOT) return;
  int n = min(fillp[w * FSTR], CAP);
  const uint2* bs = bins + (size_t)w * CAP;
  float a = 0.0f;
  int k = 0;
  for (; k + 4 <= n; k += 4) {
    uint2 e0 = bs[k];
    uint2 e1 = bs[k + 1];
    uint2 e2 = bs[k + 2];
    uint2 e3 = bs[k + 3];
    int c0 = (int)e0.x; float v0 = __uint_as_float(e0.y);
    int c1 = (int)e1.x; float v1 = __uint_as_float(e1.y);
    int c2 = (int)e2.x; float v2 = __uint_as_float(e2.y);
    int c3 = (int)e3.x; float v3 = __uint_as_float(e3.y);
    const float* x0 = (c0 < NUSERS) ? uemb + (size_t)c0 * EMB : iemb + (size_t)(c0 - NUSERS) * EMB;
    const float* x1 = (c1 < NUSERS) ? uemb + (size_t)c1 * EMB : iemb + (size_t)(c1 - NUSERS) * EMB;
    const float* x2 = (c2 < NUSERS) ? uemb + (size_t)c2 * EMB : iemb + (size_t)(c2 - NUSERS) * EMB;
    const float* x3 = (c3 < NUSERS) ? uemb + (size_t)c3 * EMB : iemb + (size_t)(c3 - NUSERS) * EMB;
    float f0 = x0[lane], f1 = x1[lane], f2 = x2[lane], f3 = x3[lane];
    a = fmaf(v0, f0, a);
    a = fmaf(v1, f1, a);
    a = fmaf(v2, f2, a);
    a = fmaf(v3, f3, a);
  }
  for (; k < n; ++k) {
    uint2 e0 = bs[k];
    int c0 = (int)e0.x; float v0 = __uint_as_float(e0.y);
    const float* x0 = (c0 < NUSERS) ? uemb + (size_t)c0 * EMB : iemb + (size_t)(c0 - NUSERS) * EMB;
    a = fmaf(v0, x0[lane], a);
  }
  acc[(size_t)w * EMB + lane] = a;
}

__global__ __launch_bounds__(256) void lg_prep(const int* __restrict__ user,
                                               const int* __restrict__ positive,
                                               const float* __restrict__ uemb,
                                               const float* __restrict__ iemb,
                                               const int* __restrict__ map,
                                               const float* __restrict__ acc,
                                               unsigned short* __restrict__ zub,
                                               unsigned short* __restrict__ zib,
                                               float* __restrict__ part_align,
                                               float* __restrict__ part_reg) {
  int w = (blockIdx.x * blockDim.x + threadIdx.x) >> 6;
  int lane = threadIdx.x & 63;
  if (w >= BB) return;
  int ru = user[w];
  int pi = positive[w];
  float eu = uemb[(size_t)ru * EMB + lane];
  float ei = iemb[(size_t)pi * EMB + lane];
  int su = map[ru];
  int si = map[NUSERS + pi];
  float zul = 2.0f * eu + acc[(size_t)su * EMB + lane];
  float zil = 2.0f * ei + acc[(size_t)si * EMB + lane];
  float nu = wave_reduce_sum(zul * zul);
  float ni = wave_reduce_sum(zil * zil);
  float un = zul * rsqrtf(nu + EPSN);
  float inn = zil * rsqrtf(ni + EPSN);
  zub[(size_t)w * EMB + lane] = f2bf(un);
  zib[(size_t)w * EMB + lane] = f2bf(inn);
  float d = un - inn;
  float align_b = wave_reduce_sum(d * d);
  float reg_b = wave_reduce_sum(eu * eu + ei * ei);
  if (lane == 0) {
    part_align[w] = align_b;
    part_reg[w] = reg_b;
  }
}

// MFMA gram with LDS-staged panels (coalesced global loads, XOR swizzle).
__global__ __launch_bounds__(256) void lg_gram_mfma(const unsigned short* __restrict__ zub,
                                                    const unsigned short* __restrict__ zib,
                                                    float* __restrict__ gpart) {
  int L = blockIdx.x, m = blockIdx.y;
  int ib = 0, rem = L;
  while (rem >= NT - ib) { rem -= NT - ib; ++ib; }
  int jb = ib + rem;
  const unsigned short* z = (m == 0) ? zub : zib;
  __shared__ uint4 As4[1024];   // 16 KB: row r (0..127), seg s (0..7) at [r*8 + (s^(r&7))]
  __shared__ uint4 Bs4[1024];
  __shared__ float wsum[4];
  int t = threadIdx.x;
  const uint4* srcA = (const uint4*)(z + (size_t)ib * 128 * EMB);
  const uint4* srcB = (const uint4*)(z + (size_t)jb * 128 * EMB);
  #pragma unroll
  for (int it = 0; it < 4; ++it) {
    int idx = it * 256 + t;           // 0..1023, coalesced 16-B loads
    int r = idx >> 3, s = idx & 7;
    int dst = r * 8 + (s ^ (r & 7));  // XOR swizzle in 16-B units
    As4[dst] = srcA[idx];
    Bs4[dst] = srcB[idx];
  }
  __syncthreads();
  int l = t & 63, w = t >> 6;
  int wr = w >> 1, wc = w & 1;
  int lr = l & 31;
  int h = l >> 5;
  int ra0 = wr * 64 + lr;
  int ra1 = ra0 + 32;
  int rb0 = wc * 64 + lr;
  int rb1 = rb0 + 32;
  f32x16 a00 = {}, a01 = {}, a10 = {}, a11 = {};
  #pragma unroll
  for (int ks = 0; ks < 4; ++ks) {
    int seg = ks * 2 + h;
    short8v a0 = *(const short8v*)&As4[ra0 * 8 + (seg ^ (ra0 & 7))];
    short8v a1 = *(const short8v*)&As4[ra1 * 8 + (seg ^ (ra1 & 7))];
    short8v b0 = *(const short8v*)&Bs4[rb0 * 8 + (seg ^ (rb0 & 7))];
    short8v b1 = *(const short8v*)&Bs4[rb1 * 8 + (seg ^ (rb1 & 7))];
    a00 = __builtin_amdgcn_mfma_f32_32x32x16_bf16(a0, b0, a00, 0, 0, 0);
    a01 = __builtin_amdgcn_mfma_f32_32x32x16_bf16(a0, b1, a01, 0, 0, 0);
    a10 = __builtin_amdgcn_mfma_f32_32x32x16_bf16(a1, b0, a10, 0, 0, 0);
    a11 = __builtin_amdgcn_mfma_f32_32x32x16_bf16(a1, b1, a11, 0, 0, 0);
  }
  float s = 0.0f;
  #pragma unroll
  for (int e = 0; e < 16; ++e) {
    s += __expf(-2.0f * fmaxf(fmaf(-2.0f, a00[e], 2.0f), 0.0f));
    s += __expf(-2.0f * fmaxf(fmaf(-2.0f, a01[e], 2.0f), 0.0f));
    s += __expf(-2.0f * fmaxf(fmaf(-2.0f, a10[e], 2.0f), 0.0f));
    s += __expf(-2.0f * fmaxf(fmaf(-2.0f, a11[e], 2.0f), 0.0f));
  }
  s = wave_reduce_sum(s);
  if (l == 0) wsum[w] = s;
  __syncthreads();
  if (t == 0) {
    float tot = wsum[0] + wsum[1] + wsum[2] + wsum[3];
    float wgt = (ib == jb) ? 1.0f : 2.0f;   // S_full = 2*S_tri + S_diag
    gpart[m * NTRI + L] = wgt * tot;
  }
}

__global__ __launch_bounds__(256) void lg_final(const float* __restrict__ part_align,
                                                const float* __restrict__ part_reg,
                                                const float* __restrict__ gpart,
                                                float* __restrict__ out) {
  __shared__ float red[4][4];
  int t = threadIdx.x;
  float sa = 0.0f, sr = 0.0f, su = 0.0f, si = 0.0f;
  for (int k = t; k < 4096; k += 256) {
    sa += part_align[k];
    sr += part_reg[k];
  }
  for (int k = t; k < NTRI; k += 256) {
    su += gpart[k];
    si += gpart[NTRI + k];
  }
  sa = wave_reduce_sum(sa);
  sr = wave_reduce_sum(sr);
  su = wave_reduce_sum(su);
  si = wave_reduce_sum(si);
  if ((t & 63) == 0) {
    int wid = t >> 6;
    red[wid][0] = sa; red[wid][1] = sr; red[wid][2] = su; red[wid][3] = si;
  }
  __syncthreads();
  if (t == 0) {
    float a = 0, r = 0, Su = 0, Si = 0;
    #pragma unroll
    for (int wv = 0; wv < 4; ++wv) {
      a += red[wv][0]; r += red[wv][1]; Su += red[wv][2]; Si += red[wv][3];
    }
    float align = a / (float)BB;
    float reg = 1e-4f * 0.5f * r / (float)BB;
    float npairs = (float)BB * (float)(BB - 1) * 0.5f;
    float tri_u = (Su - (float)BB) * 0.5f;
    float tri_i = (Si - (float)BB) * 0.5f;
    float Lu = logf(tri_u / npairs);
    float Li = logf(tri_i / npairs);
    out[0] = align;
    out[1] = 0.5f * (Lu + Li);
    out[2] = reg;
  }
}

extern "C" void kernel_launch(void* const* d_in, const int* in_sizes, int n_in,
                              void* d_out, int out_size, void* d_ws, size_t ws_size,
                              hipStream_t stream) {
  const int* user = (const int*)d_in[0];
  const int* positive = (const int*)d_in[1];
  const int* adj_rows = (const int*)d_in[3];
  const int* adj_cols = (const int*)d_in[4];
  const float* adj_vals = (const float*)d_in[5];
  const float* uemb = (const float*)d_in[6];
  const float* iemb = (const float*)d_in[7];

  char* ws = (char*)d_ws;
  int* map = (int*)(ws);
  int* fillp = (int*)(ws + (1u << 20));
  uint2* bins = (uint2*)(ws + (2u << 20));
  float* acc = (float*)(ws + (10u << 20));
  unsigned short* zub = (unsigned short*)(ws + (12u << 20));
  unsigned short* zib = (unsigned short*)(ws + (12u << 20) + (512u << 10));
  float* part_align = (float*)(ws + (13u << 20));
  float* part_reg = (float*)(ws + (13u << 20) + (16u << 10));
  float* gpart = (float*)(ws + (13u << 20) + (32u << 10));
  unsigned* bitmap = (unsigned*)(ws + (13u << 20) + (64u << 10));
  unsigned char* hitmask = (unsigned char*)(ws + (14u << 20));
  float* out = (float*)d_out;

  lg_init<<<dim3(1024), dim3(256), 0, stream>>>(map, fillp, bitmap);
  lg_mark<<<dim3(32), dim3(256), 0, stream>>>(user, positive, map, bitmap);
  lg_probe<<<dim3((NG + 255) / 256), dim3(256), 0, stream>>>(
      (const int4*)adj_rows, bitmap, hitmask);
  lg_collect<<<dim3((NM4 + 255) / 256), dim3(256), 0, stream>>>(
      (const unsigned*)hitmask, adj_rows, adj_cols, adj_vals, map, fillp, bins);
  lg_accum<<<dim3(NSLOT / 4), dim3(256), 0, stream>>>(fillp, bins, uemb, iemb, acc);
  lg_prep<<<dim3(1024), dim3(256), 0, stream>>>(user, positive, uemb, iemb, map,
                                                acc, zub, zib, part_align, part_reg);
  lg_gram_mfma<<<dim3(NTRI, 2), dim3(256), 0, stream>>>(zub, zib, gpart);
  lg_final<<<dim3(1), dim3(256), 0, stream>>>(part_align, part_reg, gpart, out);
}

// Round 17
// 60.856 us; speedup vs baseline: 1.1397x; 1.1397x over previous
//
#include <hip/hip_runtime.h>
#include <math.h>

#define NUSERS 100000
#define NITEMS 50000
#define NN (NUSERS + NITEMS)
#define EMB 64
#define NNZ_ 4000000
#define BB 4096
#define NSLOT (2 * BB)
#define CAP 128
#define FSTR 32            // fill counter stride (ints): 1 counter per 128-B line
#define BMW 4688           // bitmap words: ceil(150000/32)
#define EPSN 1e-12f
#define NT 32              // 4096 / 128 gram tiles per side
#define NTRI 528           // NT*(NT+1)/2 upper-tri tiles
#define NG (NNZ_ / 4)      // 1,000,000 int4 groups
#define SGRID 2048         // scan blocks; 2048*256*2 groups >= NG

// ws layout (bytes):
//  map        : int[NN]            @ 0        (1 MiB reserved)
//  fillp      : int[NSLOT*FSTR]    @ 1 MiB    (1 MiB)
//  bins       : uint2[NSLOT*CAP]   @ 2 MiB    (8 MiB)
//  acc        : float[NSLOT*EMB]   @ 10 MiB   (2 MiB)
//  zub        : ushort[BB*EMB]     @ 12 MiB   (512 KiB)
//  zib        : ushort[BB*EMB]     @ 12.5 MiB (512 KiB)
//  part_align : float[BB]          @ 13 MiB
//  part_reg   : float[BB]          @ 13 MiB + 16 KiB
//  gpart      : float[2*NTRI]      @ 13 MiB + 32 KiB
//  bitmap     : uint[BMW]          @ 13 MiB + 64 KiB

typedef __attribute__((ext_vector_type(8))) short short8v;
typedef __attribute__((ext_vector_type(16))) float f32x16;

__device__ inline float wave_reduce_sum(float v) {
  #pragma unroll
  for (int off = 32; off >= 1; off >>= 1) v += __shfl_xor(v, off, 64);
  return v;
}

__device__ inline unsigned short f2bf(float f) {
  unsigned u = __float_as_uint(f);
  unsigned r = u + 0x7fffu + ((u >> 16) & 1u);
  return (unsigned short)(r >> 16);
}

__global__ __launch_bounds__(256) void lg_init(int* map, int* fillp, unsigned* bitmap) {
  int t = blockIdx.x * blockDim.x + threadIdx.x;
  if (t < NN) map[t] = -1;
  if (t < NSLOT * FSTR) fillp[t] = 0;
  if (t < BMW) bitmap[t] = 0u;
}

__global__ __launch_bounds__(256) void lg_mark(const int* __restrict__ user,
                                               const int* __restrict__ positive,
                                               int* __restrict__ map,
                                               unsigned* __restrict__ bitmap) {
  int t = blockIdx.x * blockDim.x + threadIdx.x;
  if (t >= 2 * BB) return;
  int row = (t < BB) ? user[t] : (NUSERS + positive[t - BB]);
  atomicCAS(&map[row], -1, t);
  atomicOr(&bitmap[row >> 5], 1u << (row & 31));
}

// Rows-ONLY stream (16 MB vs 48 MB): ballot-compact hit {row,k} pairs,
// single drain fetches cols[k]/vals[k]/map[r] as 3 INDEPENDENT scattered
// gathers per hit (~220K x 12 B total). accum stays byte-identical to R13.
__global__ __launch_bounds__(256) void lg_scan_bin(const int4* __restrict__ rows4,
                                                   const int* __restrict__ cols,
                                                   const float* __restrict__ vals,
                                                   const unsigned* __restrict__ bitmap,
                                                   const int* __restrict__ map,
                                                   int* __restrict__ fillp,
                                                   uint2* __restrict__ bins) {
  __shared__ int qr[4][512];
  __shared__ int qk[4][512];
  int t = threadIdx.x;
  int lane = t & 63, w = t >> 6;
  unsigned long long lmlt = (1ull << lane) - 1ull;
  const int STR = SGRID * 256;         // 524288
  int g0 = blockIdx.x * 256 + t;       // always < NG
  int g1 = g0 + STR;
  bool v1 = g1 < NG;
  // issue both stream loads up-front (MLP)
  int4 r0 = rows4[g0];
  int4 r1 = v1 ? rows4[g1] : make_int4(0, 0, 0, 0);
  // 8 independent probes
  bool h0 = ((bitmap[r0.x >> 5] >> (r0.x & 31)) & 1u);
  bool h1 = ((bitmap[r0.y >> 5] >> (r0.y & 31)) & 1u);
  bool h2 = ((bitmap[r0.z >> 5] >> (r0.z & 31)) & 1u);
  bool h3 = ((bitmap[r0.w >> 5] >> (r0.w & 31)) & 1u);
  bool h4 = v1 && ((bitmap[r1.x >> 5] >> (r1.x & 31)) & 1u);
  bool h5 = v1 && ((bitmap[r1.y >> 5] >> (r1.y & 31)) & 1u);
  bool h6 = v1 && ((bitmap[r1.z >> 5] >> (r1.z & 31)) & 1u);
  bool h7 = v1 && ((bitmap[r1.w >> 5] >> (r1.w & 31)) & 1u);
  int k0 = g0 * 4, k1 = g1 * 4;
  int qn = 0;
  #define ENQ(hh, rr, kk)                                                   \
  {                                                                         \
    unsigned long long m = __ballot(hh);                                    \
    if (hh) { int p = qn + (int)__popcll(m & lmlt); qr[w][p] = (rr);        \
              qk[w][p] = (kk); }                                            \
    qn += (int)__popcll(m);                                                 \
  }
  ENQ(h0, r0.x, k0 + 0)
  ENQ(h1, r0.y, k0 + 1)
  ENQ(h2, r0.z, k0 + 2)
  ENQ(h3, r0.w, k0 + 3)
  ENQ(h4, r1.x, k1 + 0)
  ENQ(h5, r1.y, k1 + 1)
  ENQ(h6, r1.z, k1 + 2)
  ENQ(h7, r1.w, k1 + 3)
  #undef ENQ
  // single drain: 3 independent gathers -> atomic -> scattered store
  for (int i = lane; i < qn; i += 64) {
    int rr = qr[w][i];
    int kk = qk[w][i];
    int s = map[rr];
    int c = cols[kk];
    float fv = vals[kk];
    int pos = atomicAdd(&fillp[s * FSTR], 1);
    if (pos < CAP) bins[(size_t)s * CAP + pos] = make_uint2((unsigned)c, __float_as_uint(fv));
  }
}

__global__ __launch_bounds__(256) void lg_accum(const int* __restrict__ fillp,
                                                const uint2* __restrict__ bins,
                                                const float* __restrict__ uemb,
                                                const float* __restrict__ iemb,
                                                float* __restrict__ acc) {
  int w = (blockIdx.x * blockDim.x + threadIdx.x) >> 6;
  int lane = threadIdx.x & 63;
  if (w >= NSLOT) return;
  int n = min(fillp[w * FSTR], CAP);
  const uint2* bs = bins + (size_t)w * CAP;
  float a = 0.0f;
  int k = 0;
  for (; k + 4 <= n; k += 4) {
    uint2 e0 = bs[k];
    uint2 e1 = bs[k + 1];
    uint2 e2 = bs[k + 2];
    uint2 e3 = bs[k + 3];
    int c0 = (int)e0.x; float v0 = __uint_as_float(e0.y);
    int c1 = (int)e1.x; float v1 = __uint_as_float(e1.y);
    int c2 = (int)e2.x; float v2 = __uint_as_float(e2.y);
    int c3 = (int)e3.x; float v3 = __uint_as_float(e3.y);
    const float* x0 = (c0 < NUSERS) ? uemb + (size_t)c0 * EMB : iemb + (size_t)(c0 - NUSERS) * EMB;
    const float* x1 = (c1 < NUSERS) ? uemb + (size_t)c1 * EMB : iemb + (size_t)(c1 - NUSERS) * EMB;
    const float* x2 = (c2 < NUSERS) ? uemb + (size_t)c2 * EMB : iemb + (size_t)(c2 - NUSERS) * EMB;
    const float* x3 = (c3 < NUSERS) ? uemb + (size_t)c3 * EMB : iemb + (size_t)(c3 - NUSERS) * EMB;
    float f0 = x0[lane], f1 = x1[lane], f2 = x2[lane], f3 = x3[lane];
    a = fmaf(v0, f0, a);
    a = fmaf(v1, f1, a);
    a = fmaf(v2, f2, a);
    a = fmaf(v3, f3, a);
  }
  for (; k < n; ++k) {
    uint2 e0 = bs[k];
    int c0 = (int)e0.x; float v0 = __uint_as_float(e0.y);
    const float* x0 = (c0 < NUSERS) ? uemb + (size_t)c0 * EMB : iemb + (size_t)(c0 - NUSERS) * EMB;
    a = fmaf(v0, x0[lane], a);
  }
  acc[(size_t)w * EMB + lane] = a;
}

__global__ __launch_bounds__(256) void lg_prep(const int* __restrict__ user,
                                               const int* __restrict__ positive,
                                               const float* __restrict__ uemb,
                                               const float* __restrict__ iemb,
                                               const int* __restrict__ map,
                                               const float* __restrict__ acc,
                                               unsigned short* __restrict__ zub,
                                               unsigned short* __restrict__ zib,
                                               float* __restrict__ part_align,
                                               float* __restrict__ part_reg) {
  int w = (blockIdx.x * blockDim.x + threadIdx.x) >> 6;
  int lane = threadIdx.x & 63;
  if (w >= BB) return;
  int ru = user[w];
  int pi = positive[w];
  float eu = uemb[(size_t)ru * EMB + lane];
  float ei = iemb[(size_t)pi * EMB + lane];
  int su = map[ru];
  int si = map[NUSERS + pi];
  float zul = 2.0f * eu + acc[(size_t)su * EMB + lane];
  float zil = 2.0f * ei + acc[(size_t)si * EMB + lane];
  float nu = wave_reduce_sum(zul * zul);
  float ni = wave_reduce_sum(zil * zil);
  float un = zul * rsqrtf(nu + EPSN);
  float inn = zil * rsqrtf(ni + EPSN);
  zub[(size_t)w * EMB + lane] = f2bf(un);
  zib[(size_t)w * EMB + lane] = f2bf(inn);
  float d = un - inn;
  float align_b = wave_reduce_sum(d * d);
  float reg_b = wave_reduce_sum(eu * eu + ei * ei);
  if (lane == 0) {
    part_align[w] = align_b;
    part_reg[w] = reg_b;
  }
}

// MFMA gram with LDS-staged panels (coalesced global loads, XOR swizzle).
__global__ __launch_bounds__(256) void lg_gram_mfma(const unsigned short* __restrict__ zub,
                                                    const unsigned short* __restrict__ zib,
                                                    float* __restrict__ gpart) {
  int L = blockIdx.x, m = blockIdx.y;
  int ib = 0, rem = L;
  while (rem >= NT - ib) { rem -= NT - ib; ++ib; }
  int jb = ib + rem;
  const unsigned short* z = (m == 0) ? zub : zib;
  __shared__ uint4 As4[1024];   // 16 KB: row r (0..127), seg s (0..7) at [r*8 + (s^(r&7))]
  __shared__ uint4 Bs4[1024];
  __shared__ float wsum[4];
  int t = threadIdx.x;
  const uint4* srcA = (const uint4*)(z + (size_t)ib * 128 * EMB);
  const uint4* srcB = (const uint4*)(z + (size_t)jb * 128 * EMB);
  #pragma unroll
  for (int it = 0; it < 4; ++it) {
    int idx = it * 256 + t;           // 0..1023, coalesced 16-B loads
    int r = idx >> 3, s = idx & 7;
    int dst = r * 8 + (s ^ (r & 7));  // XOR swizzle in 16-B units
    As4[dst] = srcA[idx];
    Bs4[dst] = srcB[idx];
  }
  __syncthreads();
  int l = t & 63, w = t >> 6;
  int wr = w >> 1, wc = w & 1;
  int lr = l & 31;
  int h = l >> 5;
  int ra0 = wr * 64 + lr;
  int ra1 = ra0 + 32;
  int rb0 = wc * 64 + lr;
  int rb1 = rb0 + 32;
  f32x16 a00 = {}, a01 = {}, a10 = {}, a11 = {};
  #pragma unroll
  for (int ks = 0; ks < 4; ++ks) {
    int seg = ks * 2 + h;
    short8v a0 = *(const short8v*)&As4[ra0 * 8 + (seg ^ (ra0 & 7))];
    short8v a1 = *(const short8v*)&As4[ra1 * 8 + (seg ^ (ra1 & 7))];
    short8v b0 = *(const short8v*)&Bs4[rb0 * 8 + (seg ^ (rb0 & 7))];
    short8v b1 = *(const short8v*)&Bs4[rb1 * 8 + (seg ^ (rb1 & 7))];
    a00 = __builtin_amdgcn_mfma_f32_32x32x16_bf16(a0, b0, a00, 0, 0, 0);
    a01 = __builtin_amdgcn_mfma_f32_32x32x16_bf16(a0, b1, a01, 0, 0, 0);
    a10 = __builtin_amdgcn_mfma_f32_32x32x16_bf16(a1, b0, a10, 0, 0, 0);
    a11 = __builtin_amdgcn_mfma_f32_32x32x16_bf16(a1, b1, a11, 0, 0, 0);
  }
  float s = 0.0f;
  #pragma unroll
  for (int e = 0; e < 16; ++e) {
    s += __expf(-2.0f * fmaxf(fmaf(-2.0f, a00[e], 2.0f), 0.0f));
    s += __expf(-2.0f * fmaxf(fmaf(-2.0f, a01[e], 2.0f), 0.0f));
    s += __expf(-2.0f * fmaxf(fmaf(-2.0f, a10[e], 2.0f), 0.0f));
    s += __expf(-2.0f * fmaxf(fmaf(-2.0f, a11[e], 2.0f), 0.0f));
  }
  s = wave_reduce_sum(s);
  if (l == 0) wsum[w] = s;
  __syncthreads();
  if (t == 0) {
    float tot = wsum[0] + wsum[1] + wsum[2] + wsum[3];
    float wgt = (ib == jb) ? 1.0f : 2.0f;   // S_full = 2*S_tri + S_diag
    gpart[m * NTRI + L] = wgt * tot;
  }
}

__global__ __launch_bounds__(256) void lg_final(const float* __restrict__ part_align,
                                                const float* __restrict__ part_reg,
                                                const float* __restrict__ gpart,
                                                float* __restrict__ out) {
  __shared__ float red[4][4];
  int t = threadIdx.x;
  float sa = 0.0f, sr = 0.0f, su = 0.0f, si = 0.0f;
  for (int k = t; k < 4096; k += 256) {
    sa += part_align[k];
    sr += part_reg[k];
  }
  for (int k = t; k < NTRI; k += 256) {
    su += gpart[k];
    si += gpart[NTRI + k];
  }
  sa = wave_reduce_sum(sa);
  sr = wave_reduce_sum(sr);
  su = wave_reduce_sum(su);
  si = wave_reduce_sum(si);
  if ((t & 63) == 0) {
    int wid = t >> 6;
    red[wid][0] = sa; red[wid][1] = sr; red[wid][2] = su; red[wid][3] = si;
  }
  __syncthreads();
  if (t == 0) {
    float a = 0, r = 0, Su = 0, Si = 0;
    #pragma unroll
    for (int wv = 0; wv < 4; ++wv) {
      a += red[wv][0]; r += red[wv][1]; Su += red[wv][2]; Si += red[wv][3];
    }
    float align = a / (float)BB;
    float reg = 1e-4f * 0.5f * r / (float)BB;
    float npairs = (float)BB * (float)(BB - 1) * 0.5f;
    float tri_u = (Su - (float)BB) * 0.5f;
    float tri_i = (Si - (float)BB) * 0.5f;
    float Lu = logf(tri_u / npairs);
    float Li = logf(tri_i / npairs);
    out[0] = align;
    out[1] = 0.5f * (Lu + Li);
    out[2] = reg;
  }
}

extern "C" void kernel_launch(void* const* d_in, const int* in_sizes, int n_in,
                              void* d_out, int out_size, void* d_ws, size_t ws_size,
                              hipStream_t stream) {
  const int* user = (const int*)d_in[0];
  const int* positive = (const int*)d_in[1];
  const int* adj_rows = (const int*)d_in[3];
  const int* adj_cols = (const int*)d_in[4];
  const float* adj_vals = (const float*)d_in[5];
  const float* uemb = (const float*)d_in[6];
  const float* iemb = (const float*)d_in[7];

  char* ws = (char*)d_ws;
  int* map = (int*)(ws);
  int* fillp = (int*)(ws + (1u << 20));
  uint2* bins = (uint2*)(ws + (2u << 20));
  float* acc = (float*)(ws + (10u << 20));
  unsigned short* zub = (unsigned short*)(ws + (12u << 20));
  unsigned short* zib = (unsigned short*)(ws + (12u << 20) + (512u << 10));
  float* part_align = (float*)(ws + (13u << 20));
  float* part_reg = (float*)(ws + (13u << 20) + (16u << 10));
  float* gpart = (float*)(ws + (13u << 20) + (32u << 10));
  unsigned* bitmap = (unsigned*)(ws + (13u << 20) + (64u << 10));
  float* out = (float*)d_out;

  lg_init<<<dim3(1024), dim3(256), 0, stream>>>(map, fillp, bitmap);
  lg_mark<<<dim3(32), dim3(256), 0, stream>>>(user, positive, map, bitmap);
  lg_scan_bin<<<dim3(SGRID), dim3(256), 0, stream>>>(
      (const int4*)adj_rows, adj_cols, adj_vals, bitmap, map, fillp, bins);
  lg_accum<<<dim3(NSLOT / 4), dim3(256), 0, stream>>>(fillp, bins, uemb, iemb, acc);
  lg_prep<<<dim3(1024), dim3(256), 0, stream>>>(user, positive, uemb, iemb, map,
                                                acc, zub, zib, part_align, part_reg);
  lg_gram_mfma<<<dim3(NTRI, 2), dim3(256), 0, stream>>>(zub, zib, gpart);
  lg_final<<<dim3(1), dim3(256), 0, stream>>>(part_align, part_reg, gpart, out);
}